// Round 6
// baseline (196.067 us; speedup 1.0000x reference)
//
#include <hip/hip_runtime.h>

// EmotionCaps dynamic routing (fp32 I/O):
// u: [B=64, N=1024, I=64] f32; W: [N=1024, E=8, O=32, I=64] f32
// out: v [B=64, E=8, O=32] f32
// Stage 1 (k_uhat): u_hat (bf16, 32MB ws) = per-n GEMM via bf16 MFMA,
//          B-frags streamed from global, u LDS-staged, LDS-transpose epilogue.
// Stage 2 (k_route_all): ALL 3 routing iterations + squashes in ONE kernel,
//          one block per b (64 x 1024 threads), in-block LDS reductions only.
//          Logit identity: b1 = uh.v0 ; b2 = uh.(v0+v1) — no logit storage.

#define B_  64
#define N_  1024
#define I_  64
#define E_  8
#define O_  32
#define EO_ 256
#define PAD_ 72

typedef __bf16 bf16x8 __attribute__((ext_vector_type(8)));
typedef __bf16 bf16x4v __attribute__((ext_vector_type(4)));
typedef float  f32x4  __attribute__((ext_vector_type(4)));

__device__ __forceinline__ float bf2f(unsigned int h) {
    unsigned int x = (h & 0xffffu) << 16;
    return __builtin_bit_cast(float, x);
}
__device__ __forceinline__ unsigned short f2bf(float f) {
    unsigned int x = __builtin_bit_cast(unsigned int, f);
    unsigned int r = x + 0x7fffu + ((x >> 16) & 1u);   // RNE
    return (unsigned short)(r >> 16);
}
__device__ __forceinline__ void cvt_store4(unsigned short* dst, float4 q) {
    bf16x4v v;
    v[0] = (__bf16)q.x; v[1] = (__bf16)q.y; v[2] = (__bf16)q.z; v[3] = (__bf16)q.w;
    *(bf16x4v*)dst = v;
}
__device__ __forceinline__ bf16x8 cvt8(const float* __restrict__ p) {
    float4 q0 = *(const float4*)p;
    float4 q1 = *(const float4*)(p + 4);
    bf16x8 a;
    a[0] = (__bf16)q0.x; a[1] = (__bf16)q0.y; a[2] = (__bf16)q0.z; a[3] = (__bf16)q0.w;
    a[4] = (__bf16)q1.x; a[5] = (__bf16)q1.y; a[6] = (__bf16)q1.z; a[7] = (__bf16)q1.w;
    return a;
}

// ---------------------------------------------------------------------------
// K1: one block per n. D[64b x 256eo] = u[:,n,:] . W[n]^T via 16x16x32 bf16
// MFMA (fragment layouts verified rounds 3-5). u staged in LDS (A-frags);
// W frags streamed from global; D transposed through LDS for coalesced stores.
// ---------------------------------------------------------------------------
__global__ __launch_bounds__(256) void k_uhat(const float* __restrict__ u,
                                              const float* __restrict__ W,
                                              unsigned short* __restrict__ uh) {
    const int n = blockIdx.x;
    const int t = threadIdx.x;
    const int w = t >> 6, l = t & 63;
    const int m16 = l & 15, g = l >> 4;

    __shared__ __align__(16) unsigned short ul[B_ * PAD_];      //  9216 B
    __shared__ __align__(16) unsigned short Dt[B_ * 264];       // 33792 B

#pragma unroll
    for (int j = 0; j < 4; ++j) {
        int idx = j * 256 + t;
        int b = idx >> 4, c = idx & 15;
        float4 q = *(const float4*)(u + (size_t)b * (N_ * I_) + n * I_ + c * 4);
        cvt_store4(&ul[b * PAD_ + c * 4], q);
    }
    __syncthreads();

    bf16x8 afr[4][2];   // A[m=lane&15][k=(lane>>4)*8+j]
#pragma unroll
    for (int mt = 0; mt < 4; ++mt)
#pragma unroll
        for (int ks = 0; ks < 2; ++ks)
            afr[mt][ks] = *(const bf16x8*)&ul[(mt * 16 + m16) * PAD_ + ks * 32 + g * 8];

    f32x4 acc[4][4];
#pragma unroll
    for (int nt = 0; nt < 4; ++nt)
#pragma unroll
        for (int mt = 0; mt < 4; ++mt)
            acc[nt][mt] = (f32x4){0.f, 0.f, 0.f, 0.f};

    const float* Wn = W + (size_t)n * (EO_ * I_);
#pragma unroll
    for (int nt = 0; nt < 4; ++nt) {
        const int eo = w * 64 + nt * 16 + m16;
        const float* wp = Wn + (size_t)eo * I_ + g * 8;
        bf16x8 b0 = cvt8(wp);
        bf16x8 b1 = cvt8(wp + 32);
#pragma unroll
        for (int mt = 0; mt < 4; ++mt) {
            acc[nt][mt] = __builtin_amdgcn_mfma_f32_16x16x32_bf16(afr[mt][0], b0, acc[nt][mt], 0, 0, 0);
            acc[nt][mt] = __builtin_amdgcn_mfma_f32_16x16x32_bf16(afr[mt][1], b1, acc[nt][mt], 0, 0, 0);
        }
    }

    // D lane map: col=lane&15, row=(lane>>4)*4+reg -> LDS transpose
#pragma unroll
    for (int nt = 0; nt < 4; ++nt) {
        const int col = w * 64 + nt * 16 + m16;
#pragma unroll
        for (int mt = 0; mt < 4; ++mt)
#pragma unroll
            for (int r = 0; r < 4; ++r)
                Dt[(mt * 16 + g * 4 + r) * 264 + col] = f2bf(acc[nt][mt][r]);
    }
    __syncthreads();
#pragma unroll
    for (int r = 0; r < 16; ++r) {
        const int row = r * 4 + w;
        uint2 q = *(const uint2*)&Dt[row * 264 + l * 4];
        *(uint2*)(uh + (size_t)row * (N_ * EO_) + (size_t)n * EO_ + l * 4) = q;
    }
}

// ---------------------------------------------------------------------------
// K2: the WHOLE routing phase. One block per b (64 blocks x 1024 threads).
// Wave 'wave' (0..15) streams n in [64*wave, 64*wave+64); lane l owns
// eo = 4l..4l+3 (e = l>>3). In-wave shuffle math verified rounds 2-5:
//   dot over o: shfl_xor 1,2,4 ; softmax over E: shfl_xor 8,16,32.
// it0: c = 1/8. it1: logit = uh.v0 -> vbuf = v0+v1. it2: logit = uh.(v0+v1).
// s reduced across the 16 waves in LDS; squash on waves 0..3 (t = eo);
// |s|^2 over o: shfl_xor 1..16 (o bits of lane). No global intermediates.
// ---------------------------------------------------------------------------
__global__ __launch_bounds__(1024) void k_route_all(const unsigned short* __restrict__ uh,
                                                    float* __restrict__ out) {
    const int b = blockIdx.x;
    const int t = threadIdx.x, wave = t >> 6, l = t & 63;

    __shared__ __align__(16) float red[16][EO_];   // 16 KB
    __shared__ __align__(16) float vbuf[EO_];      //  1 KB

    const unsigned short* base = uh + (size_t)b * (N_ * EO_) + 4 * l;
    float v0keep = 0.f;                            // live in threads 0..255

#pragma unroll 1
    for (int it = 0; it < 3; ++it) {
        float4 v4 = make_float4(0.f, 0.f, 0.f, 0.f);
        if (it) v4 = *(const float4*)&vbuf[4 * l];
        float a0 = 0.f, a1 = 0.f, a2 = 0.f, a3 = 0.f;
        const unsigned short* p0 = base + (size_t)(wave * 64) * EO_;
#pragma unroll 4
        for (int nn = 0; nn < 64; ++nn) {
            uint2 p = *(const uint2*)(p0 + (size_t)nn * EO_);
            float x0 = bf2f(p.x), x1 = bf2f(p.x >> 16);
            float x2 = bf2f(p.y), x3 = bf2f(p.y >> 16);
            float c;
            if (it == 0) {
                c = 0.125f;
            } else {
                float pd = x0 * v4.x + x1 * v4.y + x2 * v4.z + x3 * v4.w;
                pd += __shfl_xor(pd, 1);
                pd += __shfl_xor(pd, 2);
                pd += __shfl_xor(pd, 4);          // logit(n,e) in all 8 e-lanes
                float m = pd;
                m = fmaxf(m, __shfl_xor(m, 8));
                m = fmaxf(m, __shfl_xor(m, 16));
                m = fmaxf(m, __shfl_xor(m, 32));
                float ex = __expf(pd - m);
                float sm = ex;
                sm += __shfl_xor(sm, 8);
                sm += __shfl_xor(sm, 16);
                sm += __shfl_xor(sm, 32);
                c = ex * __builtin_amdgcn_rcpf(sm);
            }
            a0 = fmaf(c, x0, a0); a1 = fmaf(c, x1, a1);
            a2 = fmaf(c, x2, a2); a3 = fmaf(c, x3, a3);
        }
        __syncthreads();   // waves done with vbuf/red of previous iteration
        *(float4*)&red[wave][4 * l] = make_float4(a0, a1, a2, a3);
        __syncthreads();
        if (t < EO_) {     // waves 0..3: t = eo
            float sv = 0.f;
#pragma unroll
            for (int w2 = 0; w2 < 16; ++w2) sv += red[w2][t];
            float sq = sv * sv;
            sq += __shfl_xor(sq, 1);
            sq += __shfl_xor(sq, 2);
            sq += __shfl_xor(sq, 4);
            sq += __shfl_xor(sq, 8);
            sq += __shfl_xor(sq, 16);              // |s|^2 over o-group
            float nrm = sqrtf(sq);
            float vv = sq / ((1.f + sq) * (nrm + 1e-8f)) * sv;
            if (it == 0)      { v0keep = vv; vbuf[t] = vv; }
            else if (it == 1) { vbuf[t] = v0keep + vv; }
            else              { out[b * EO_ + t] = vv; }
        }
        __syncthreads();
    }
}

extern "C" void kernel_launch(void* const* d_in, const int* in_sizes, int n_in,
                              void* d_out, int out_size, void* d_ws, size_t ws_size,
                              hipStream_t stream) {
    const float* u = (const float*)d_in[0];     // f32 [64,1024,64]
    const float* W = (const float*)d_in[1];     // f32 [1024,8,32,64]
    float* out = (float*)d_out;                 // f32 [64,8,32]

    unsigned short* uh = (unsigned short*)d_ws; // 33,554,432 B  u_hat bf16

    k_uhat     <<<dim3(N_), dim3(256),  0, stream>>>(u, W, uh);
    k_route_all<<<dim3(B_), dim3(1024), 0, stream>>>(uh, out);
}